// Round 1
// baseline (398.805 us; speedup 1.0000x reference)
//
#include <hip/hip_runtime.h>

// DarkChannel: cmin over C=3, then 15x15 min-erosion (separable), +inf border.
// Fused one-kernel design:
//   phase 1: each thread = one column; van Herk sliding-min (w=15) down TY=75
//            rows, channel-min fused into loads; result -> LDS vmin[75][256].
//   phase 2: 242 threads/block do horizontal 15-min from LDS, coalesced store.
// LDS 76.8 KB -> 2 blocks/CU. Ideal HBM ~268 MB; this structure ~322 MB.

#define IMG_H 1024
#define IMG_W 1024
#define IMG_C 3
#define IMG_B 16
#define TY    75      // output rows per block (5 van-Herk groups of 15)
#define TXO   242     // output cols per block (256 input cols - 14 halo)
#define NT    256

__global__ __launch_bounds__(NT, 2)
void DarkChannel_77713138254515_kernel(const float* __restrict__ img,
                                       float* __restrict__ out) {
    __shared__ float vmin[TY][NT];

    const int t  = threadIdx.x;
    const int y0 = blockIdx.y * TY;
    const int b  = blockIdx.z;
    const int gx = blockIdx.x * TXO - 7 + t;          // this thread's input column
    const bool xok = ((unsigned)gx < IMG_W);
    const float INF = __builtin_inff();

    const size_t plane = (size_t)IMG_H * IMG_W;
    const float* imgb = img + (size_t)b * IMG_C * plane;

    // cmin load: min over 3 channels at (y, gx); OOB -> +inf (matches jnp pad)
    auto load_cmin = [&](int y) -> float {
        if (!xok || (unsigned)y >= IMG_H) return INF;
        size_t idx = (size_t)y * IMG_W + (size_t)gx;
        float v0 = imgb[idx];
        float v1 = imgb[idx + plane];
        float v2 = imgb[idx + 2 * plane];
        return fminf(v0, fminf(v1, v2));
    };

    // ---- phase 1: vertical sliding min, van Herk blocks of 15 ----
    // output y in [y0, y0+TY); window start s = y-7 in block base Bg = y0-7+15g
    float cur[15];
#pragma unroll
    for (int i = 0; i < 15; ++i) cur[i] = load_cmin(y0 - 7 + i);

#pragma unroll
    for (int g = 0; g < TY / 15; ++g) {
        float nxt[15];
        const int nb = y0 - 7 + 15 * (g + 1);
#pragma unroll
        for (int i = 0; i < 15; ++i) nxt[i] = load_cmin(nb + i);

        float S[15];                 // suffix mins of cur
        S[14] = cur[14];
#pragma unroll
        for (int i = 13; i >= 0; --i) S[i] = fminf(cur[i], S[i + 1]);

        vmin[15 * g + 0][t] = S[0];  // window == cur block exactly
        float p = nxt[0];            // running prefix of nxt
#pragma unroll
        for (int i = 1; i < 15; ++i) {
            vmin[15 * g + i][t] = fminf(S[i], p);
            p = fminf(p, nxt[i]);
        }
#pragma unroll
        for (int i = 0; i < 15; ++i) cur[i] = nxt[i];
    }

    __syncthreads();

    // ---- phase 2: horizontal 15-min from LDS, coalesced global store ----
    if (t < TXO) {
        const int gxo = blockIdx.x * TXO + t;         // output column
        if (gxo < IMG_W) {
            float* outb = out + (size_t)b * plane;
            for (int r = 0; r < TY; ++r) {
                const int y = y0 + r;
                if (y >= IMG_H) break;
                float v = vmin[r][t];
#pragma unroll
                for (int k = 1; k < 15; ++k) v = fminf(v, vmin[r][t + k]);
                outb[(size_t)y * IMG_W + gxo] = v;
            }
        }
    }
}

extern "C" void kernel_launch(void* const* d_in, const int* in_sizes, int n_in,
                              void* d_out, int out_size, void* d_ws, size_t ws_size,
                              hipStream_t stream) {
    const float* img = (const float*)d_in[0];
    float* out = (float*)d_out;

    dim3 grid((IMG_W + TXO - 1) / TXO,   // 5
              (IMG_H + TY - 1) / TY,     // 14
              IMG_B);                    // 16
    dim3 block(NT);
    DarkChannel_77713138254515_kernel<<<grid, block, 0, stream>>>(img, out);
}

// Round 2
// 306.291 us; speedup vs baseline: 1.3020x; 1.3020x over previous
//
#include <hip/hip_runtime.h>

// DarkChannel: cmin over C=3, then 15x15 min erosion, +inf border.
// Round 2: latency fix. Each thread owns 4 columns (float4); a block's 256
// threads cover the full 1024-col width (no x-halo, no divergence). All
// global loads are unconditional dwordx4 on a clamped row index (uniform
// cndmask for OOB rows) so the compiler can batch them -> bytes in flight.
// Vertical 15-min via suffix/prefix in registers; horizontal 15-min via
// guarded LDS rows + 5x ds_read_b128. LDS 62.4 KB -> 2 blocks/CU.

#define IMG_H 1024
#define IMG_W 1024
#define IMG_C 3
#define IMG_B 16
#define TY    15
#define NT    256
#define LROW  1040   // 8 INF guard + 1024 + 8 INF guard (floats)
#define RAD   7

__device__ __forceinline__ float4 min4(float4 a, float4 b) {
    return make_float4(fminf(a.x, b.x), fminf(a.y, b.y),
                       fminf(a.z, b.z), fminf(a.w, b.w));
}

__global__ __launch_bounds__(NT, 2)
void DarkChannel_77713138254515_kernel(const float* __restrict__ img,
                                       float* __restrict__ out) {
    __shared__ float vmin[TY][LROW];

    const int t  = threadIdx.x;
    const int y0 = blockIdx.x * TY;
    const int b  = blockIdx.y;
    const int cx = 4 * t;                       // this thread's 4 columns

    const size_t plane = (size_t)IMG_H * IMG_W;
    const float* imgb = img + (size_t)b * IMG_C * plane;
    const float INF = __builtin_inff();
    const float4 INF4 = make_float4(INF, INF, INF, INF);

    // init the +/-8 column INF guards for all TY rows (240 cells)
    if (t < TY * 16) {
        int r = t >> 4, c = t & 15;
        int col = (c < 8) ? c : (IMG_W + c);    // [0,8) and [1032,1040)
        vmin[r][col] = INF;
    }

    // ---- phase 1: load 29 rows (y0-7 .. y0+21) of channel-min as float4 ----
    float4 rr[2 * TY - 1];                      // 29
#pragma unroll
    for (int i = 0; i < 2 * TY - 1; ++i) {
        const int y  = y0 - RAD + i;
        const int yc = min(max(y, 0), IMG_H - 1);   // clamped: load always legal
        const float* p0 = imgb + (size_t)yc * IMG_W + cx;
        float4 v0 = *(const float4*)(p0);
        float4 v1 = *(const float4*)(p0 + plane);
        float4 v2 = *(const float4*)(p0 + 2 * plane);
        float4 v  = min4(v0, min4(v1, v2));
        rr[i] = ((unsigned)y < IMG_H) ? v : INF4;   // uniform select, no branch
    }

    // suffix min in place over rr[0..14]: rr[i] = min(rows y .. y0+7)
#pragma unroll
    for (int i = TY - 2; i >= 0; --i) rr[i] = min4(rr[i], rr[i + 1]);

    // out[i] = min(S[i], prefix(B[0..i-1])), B = rr[15..28]
    *(float4*)&vmin[0][8 + cx] = rr[0];
    float4 p = rr[TY];
#pragma unroll
    for (int i = 1; i < TY; ++i) {
        *(float4*)&vmin[i][8 + cx] = min4(rr[i], p);
        if (i < TY - 1) p = min4(p, rr[TY + i]);
    }

    __syncthreads();

    // ---- phase 2: horizontal 15-min from guarded LDS rows ----
    const int ymax = min(TY, IMG_H - y0);
    float* outb = out + (size_t)b * plane;
    for (int r = 0; r < ymax; ++r) {
        const float* row = &vmin[r][0];
        // w[k] = img col (cx-8+k), k=0..19, via 5 aligned float4 reads
        float4 a = *(const float4*)(row + cx);        // w0..w3
        float4 bb = *(const float4*)(row + cx + 4);   // w4..w7
        float4 cc = *(const float4*)(row + cx + 8);   // w8..w11
        float4 dd = *(const float4*)(row + cx + 12);  // w12..w15
        float4 ee = *(const float4*)(row + cx + 16);  // w16..w19
        float4 m = min4(min4(bb, cc), dd);            // min w[4..15] per comp
        float core = fminf(fminf(m.x, m.y), fminf(m.z, m.w));
        float4 o;
        o.x = fminf(core, fminf(a.y, fminf(a.z, a.w)));   // w[1..15]
        o.y = fminf(core, fminf(a.z, fminf(a.w, ee.x)));  // w[2..16]
        o.z = fminf(core, fminf(a.w, fminf(ee.x, ee.y))); // w[3..17]
        o.w = fminf(core, fminf(ee.x, fminf(ee.y, ee.z)));// w[4..18]
        *(float4*)(outb + (size_t)(y0 + r) * IMG_W + cx) = o;
    }
}

extern "C" void kernel_launch(void* const* d_in, const int* in_sizes, int n_in,
                              void* d_out, int out_size, void* d_ws, size_t ws_size,
                              hipStream_t stream) {
    const float* img = (const float*)d_in[0];
    float* out = (float*)d_out;

    dim3 grid((IMG_H + TY - 1) / TY,   // 69 y-tiles
              IMG_B);                  // 16
    DarkChannel_77713138254515_kernel<<<grid, dim3(NT), 0, stream>>>(img, out);
}